// Round 7
// baseline (310.547 us; speedup 1.0000x reference)
//
#include <hip/hip_runtime.h>
#include <hip/hip_bf16.h>

// CausalSelfAttention on gfx950 — round 13.
// r12 post-mortem: BK=64 regressed qkv (94->100us): LDS 16->32KiB cut
// blocks/CU 8->5 (Occ 26->17.5) — in the drain-bound 2-phase regime,
// cross-block overlap is the hiding mechanism; occupancy loss > barrier
// halving. Third consistent data point (r9 256^2, r10 pipe, r12 BK64):
// r8 sync core at max occupancy is the local optimum for this shape.
// r13: (1) qkv reverted to r8/r11 sync core (94us twice-measured);
// (2) bijective XCD-chunked swizzle (T1) on qkv/attn/out grids — FETCH
// 71.8MB vs 22MB ideal says panels are re-fetched across XCDs; L2-hit
// staging (~200cyc vs 400-900) shortens the drain directly. out-chunk
// 8x8 = A+B 4MB = exact L2 fit; attn chunk = 8 bh -> K/V 4MB L2 fit;
// (3) setprio(1) around attn per-mi compute (T5: attn +4-7%, m191;
// independent blocks, unlike lockstep GEMM where it nulls).

typedef unsigned short u16;
typedef __attribute__((ext_vector_type(8))) short short8;
typedef __attribute__((ext_vector_type(4))) float f32x4;

#define N_HEADS 16
#define HEAD_DIM 64
#define TSEQ 2048
#define BATCH 4
#define MROWS (BATCH * TSEQ)   // 8192
#define N3 3072                // 3*D_MODEL

__device__ __forceinline__ void cp16(const u16* g, u16* l) {
  __builtin_amdgcn_global_load_lds((const __attribute__((address_space(1))) void*)g,
                                   (__attribute__((address_space(3))) void*)l, 16, 0, 0);
}

__device__ __forceinline__ f32x4 mfma16(short8 a, short8 b, f32x4 c) {
  return __builtin_amdgcn_mfma_f32_16x16x32_bf16(a, b, c, 0, 0, 0);
}

__device__ __forceinline__ u16 f2b(float f) {
  __hip_bfloat16 h = __float2bfloat16(f);
  return *reinterpret_cast<u16*>(&h);
}

// ---------------------------------------------------- fused prep kernel
#define PREP_CVT_BLOCKS 8192
#define PREP_WQKV_BLOCKS (96 * 32)
#define PREP_WOUT_BLOCKS (32 * 32)
#define PREP_TOTAL (PREP_CVT_BLOCKS + PREP_WQKV_BLOCKS + PREP_WOUT_BLOCKS)

__device__ __forceinline__ void transpose_tile(const float* __restrict__ src,
                                               u16* __restrict__ dst,
                                               int R, int Cn, int c0, int r0,
                                               float (*tile)[33]) {
  const int tx = threadIdx.x & 31, ty = threadIdx.x >> 5;
  for (int i = ty; i < 32; i += 8)
    tile[i][tx] = src[(size_t)(r0 + i) * Cn + c0 + tx];
  __syncthreads();
  for (int i = ty; i < 32; i += 8)
    dst[(size_t)(c0 + i) * R + r0 + tx] = f2b(tile[tx][i]);
}

__global__ __launch_bounds__(256) void prep_kernel(
    const float* __restrict__ x, u16* __restrict__ xb,
    const float* __restrict__ Wqkv, u16* __restrict__ wqkv_t,
    const float* __restrict__ Wout, u16* __restrict__ wout_t) {
  __shared__ float tile[32][33];
  const int bx = blockIdx.x;
  if (bx < PREP_CVT_BLOCKS) {
    int i = bx * 256 + threadIdx.x;            // n4 = 8192*256 exactly
    float4 v = *(const float4*)(x + (size_t)i * 4);
    u16* d = xb + (size_t)i * 4;
    d[0] = f2b(v.x); d[1] = f2b(v.y); d[2] = f2b(v.z); d[3] = f2b(v.w);
  } else if (bx < PREP_CVT_BLOCKS + PREP_WQKV_BLOCKS) {
    int b2 = bx - PREP_CVT_BLOCKS;
    int c0 = (b2 % 96) * 32, r0 = (b2 / 96) * 32;
    transpose_tile(Wqkv, wqkv_t, 1024, N3, c0, r0, tile);
  } else {
    int b3 = bx - PREP_CVT_BLOCKS - PREP_WQKV_BLOCKS;
    int c0 = (b3 % 32) * 32, r0 = (b3 / 32) * 32;
    transpose_tile(Wout, wout_t, 1024, 1024, c0, r0, tile);
  }
}

// ------------------------------------------ 128^2 GEMM core, SYNC variant
// r8/r11-measured 94us / MfmaUtil 22.7 on gemm_qkv. Single 16KiB LDS,
// __syncthreads-drained staging, BK=32, 8 blocks/CU. Do NOT pipeline, do
// NOT grow LDS (r9/r10/r12 all regressed).
__device__ __forceinline__ void gemm128_sync(const u16* __restrict__ A,
                                             const u16* __restrict__ Bt,
                                             int m0, int n0,
                                             u16* Asm, u16* Bsm,
                                             f32x4 acc[4][4]) {
  const int tid = threadIdx.x;
  const int w = tid >> 6;
  const int lane = tid & 63;
  const int quad = lane >> 4;
  const int l16 = lane & 15;
  const int wm = (w >> 1) * 64;
  const int wn = (w & 1) * 64;

#pragma unroll
  for (int i = 0; i < 4; ++i)
#pragma unroll
    for (int j = 0; j < 4; ++j) acc[i][j] = (f32x4){0.f, 0.f, 0.f, 0.f};

  for (int k0 = 0; k0 < 1024; k0 += 32) {
    __syncthreads();
#pragma unroll
    for (int p = 0; p < 2; ++p) {
      int s = p * 256 + tid;
      int row = s >> 2;
      int c4 = (s & 3) ^ ((row >> 1) & 3);
      cp16(A + (size_t)(m0 + row) * 1024 + k0 + c4 * 8,
           Asm + (size_t)(p * 256 + w * 64) * 8);
      cp16(Bt + (size_t)(n0 + row) * 1024 + k0 + c4 * 8,
           Bsm + (size_t)(p * 256 + w * 64) * 8);
    }
    __syncthreads();

    short8 a[4], b[4];
#pragma unroll
    for (int i = 0; i < 4; ++i) {
      int row = wm + i * 16 + l16;
      int c4 = quad ^ ((row >> 1) & 3);
      a[i] = *(const short8*)(Asm + row * 32 + c4 * 8);
    }
#pragma unroll
    for (int j = 0; j < 4; ++j) {
      int row = wn + j * 16 + l16;
      int c4 = quad ^ ((row >> 1) & 3);
      b[j] = *(const short8*)(Bsm + row * 32 + c4 * 8);
    }
#pragma unroll
    for (int i = 0; i < 4; ++i)
#pragma unroll
      for (int j = 0; j < 4; ++j)
        acc[i][j] = mfma16(a[i], b[j], acc[i][j]);
  }
}

// -------------------------------------------- 128^2 GEMM core, pipelined
// Kept for gemm_out only (r10/r11 config; untouched).
__device__ __forceinline__ void gemm128_pipe(const u16* __restrict__ A,
                                             const u16* __restrict__ Bt,
                                             int m0, int n0,
                                             u16* Asm, u16* Bsm,
                                             f32x4 acc[4][4]) {
  const int tid = threadIdx.x;
  const int w = tid >> 6;
  const int lane = tid & 63;
  const int quad = lane >> 4;
  const int l16 = lane & 15;
  const int wm = (w >> 1) * 64;
  const int wn = (w & 1) * 64;

#pragma unroll
  for (int i = 0; i < 4; ++i)
#pragma unroll
    for (int j = 0; j < 4; ++j) acc[i][j] = (f32x4){0.f, 0.f, 0.f, 0.f};

#define STG128(k0_, b_)                                                     \
  do {                                                                      \
    _Pragma("unroll")                                                       \
    for (int p = 0; p < 2; ++p) {                                           \
      int s = p * 256 + tid;                                                \
      int row = s >> 2;                                                     \
      int c4 = (s & 3) ^ ((row >> 1) & 3);                                  \
      cp16(A + (size_t)(m0 + row) * 1024 + (k0_) + c4 * 8,                  \
           Asm + (size_t)(b_) * 4096 + (p * 256 + w * 64) * 8);             \
      cp16(Bt + (size_t)(n0 + row) * 1024 + (k0_) + c4 * 8,                 \
           Bsm + (size_t)(b_) * 4096 + (p * 256 + w * 64) * 8);             \
    }                                                                       \
  } while (0)

  STG128(0, 0);
  STG128(32, 1);
  asm volatile("s_waitcnt vmcnt(4)" ::: "memory");  // tile 0 landed
  asm volatile("s_barrier" ::: "memory");

  for (int kt = 0; kt < 32; ++kt) {
    const u16* Ab = Asm + (kt & 1) * 4096;
    const u16* Bb = Bsm + (kt & 1) * 4096;
    short8 a[4], b[4];
#pragma unroll
    for (int i = 0; i < 4; ++i) {
      int row = wm + i * 16 + l16;
      int c4 = quad ^ ((row >> 1) & 3);
      a[i] = *(const short8*)(Ab + row * 32 + c4 * 8);
    }
#pragma unroll
    for (int j = 0; j < 4; ++j) {
      int row = wn + j * 16 + l16;
      int c4 = quad ^ ((row >> 1) & 3);
      b[j] = *(const short8*)(Bb + row * 32 + c4 * 8);
    }
#pragma unroll
    for (int i = 0; i < 4; ++i)
#pragma unroll
      for (int j = 0; j < 4; ++j)
        acc[i][j] = mfma16(a[i], b[j], acc[i][j]);

    asm volatile("s_barrier" ::: "memory");  // all waves done reading buf
    if (kt + 2 < 32) {
      STG128((kt + 2) * 32, kt & 1);         // into freed buf; stays in flight
      asm volatile("s_waitcnt vmcnt(4)" ::: "memory");  // tile kt+1 landed
    } else if (kt + 1 < 32) {
      asm volatile("s_waitcnt vmcnt(0)" ::: "memory");  // last tile: drain
    }
    asm volatile("s_barrier" ::: "memory");  // buf(kt+1) ready for all waves
  }
#undef STG128
}

// ---------------------------------------------------------------- QKV GEMM
// Grid (24,64) = 1536 blocks, divisible by 8. XCD-chunked swizzle: XCD x
// gets contiguous swz range [x*192,(x+1)*192) = 8 m-panels x 24 n-tiles;
// hot A-panel (256KB) stays in that XCD's L2 across its 24 n-tiles.
__global__ __launch_bounds__(256) void gemm_qkv_kernel(
    const u16* __restrict__ x, const u16* __restrict__ Wt,
    const float* __restrict__ bias,
    u16* __restrict__ qb, u16* __restrict__ kb, u16* __restrict__ vtb) {
  __shared__ __align__(16) u16 Asm[128 * 32];
  __shared__ __align__(16) u16 Bsm[128 * 32];
  f32x4 acc[4][4];
  const int flat = blockIdx.y * 24 + blockIdx.x;
  const int swz = (flat & 7) * 192 + (flat >> 3);   // bijective (1536%8==0)
  const int m0 = (swz / 24) * 128;
  const int n0 = (swz % 24) * 128;
  gemm128_sync(x, Wt, m0, n0, Asm, Bsm, acc);

  const int tid = threadIdx.x;
  const int w = tid >> 6, lane = tid & 63, quad = lane >> 4, l16 = lane & 15;
  const int wm = (w >> 1) * 64, wn = (w & 1) * 64;
#pragma unroll
  for (int j = 0; j < 4; ++j) {
    int col = n0 + wn + j * 16 + l16;
    float bv = bias[col];
    int which = col >> 10;     // 0=q 1=k 2=v
    int rem = col & 1023;
    int h = rem >> 6, d = rem & 63;
#pragma unroll
    for (int i = 0; i < 4; ++i) {
#pragma unroll
      for (int r = 0; r < 4; ++r) {
        int m = m0 + wm + i * 16 + quad * 4 + r;
        int b_ = m >> 11, t = m & 2047;
        int bh = b_ * N_HEADS + h;
        u16 o = f2b(acc[i][j][r] + bv);
        if (which == 0)
          qb[((size_t)(bh * TSEQ + t) << 6) + d] = o;
        else if (which == 1)
          kb[((size_t)(bh * TSEQ + t) << 6) + d] = o;
        else
          vtb[((size_t)((bh << 6) + d)) * TSEQ + t] = o;
      }
    }
  }
}

// ---------------------------------------------------------------- attention
// Swapped QK^T + bit-permuted K staging; P in-register (see r8 header).
// r13: XCD-chunked swizzle — each XCD gets 8 bh x 16 qt, so its K/V working
// set (8 x 512KB) = 4MB = exact L2 fit; qt still descending (heavy-first)
// within each bh. setprio(1) around per-mi compute (T5, attn-positive m191).
__global__ __launch_bounds__(256, 5) void attn_kernel(const u16* __restrict__ qb,
                                                      const u16* __restrict__ kb,
                                                      const u16* __restrict__ vtb,
                                                      u16* __restrict__ ob) {
  const int flat = blockIdx.y * 16 + blockIdx.x;
  const int swz = (flat & 7) * 128 + (flat >> 3);   // bijective (1024%8==0)
  const int bh = swz >> 4;                          // 0..63
  const int qt = 15 - (swz & 15);                   // 15..0 heavy-first
  __shared__ __align__(16) u16 Ksm[2][4096];     // [buf][rho 64][d 64] swizzled
  __shared__ __align__(16) u16 Vsm[2][4096];     // [buf][d 64][t_k 64] swizzled
  const int tid = threadIdx.x;
  const int w = tid >> 6, lane = tid & 63, quad = lane >> 4, l16 = lane & 15;
  const int qbase = qt * 128;

  // Q fragments (B-operand layout == A-layout for 16x16x32), in registers
  short8 qf[2][2];
#pragma unroll
  for (int mi = 0; mi < 2; ++mi) {
    const u16* qr = qb + ((size_t)(bh * TSEQ + qbase + mi * 64 + w * 16 + l16)) * 64;
    qf[mi][0] = *(const short8*)(qr + quad * 8);
    qf[mi][1] = *(const short8*)(qr + 32 + quad * 8);
  }

  f32x4 o[2][4];
  float lp[2] = {0.f, 0.f};
#pragma unroll
  for (int mi = 0; mi < 2; ++mi)
#pragma unroll
    for (int j = 0; j < 4; ++j) o[mi][j] = (f32x4){0.f, 0.f, 0.f, 0.f};
  const float cexp = 0.18033688011112042f;  // (1/sqrt(64)) * log2(e)
  const float M = 10.0f;                    // static softmax shift

  const u16* kb_bh = kb + (size_t)bh * TSEQ * 64;
  const u16* vt_bh = vtb + (size_t)bh * 64 * TSEQ;
  const int nk = 2 * qt + 2;

  // stage k-tile kt into buffer b: 4 DMA issues per thread (vmcnt +=4).
  // K rows bit-permuted: LDS row rho <- key kappa(rho); V rows natural (d).
#define STAGE(kt_, b_)                                                        \
  do {                                                                        \
    const u16* kbase_ = kb_bh + (size_t)((kt_) * 64) * 64;                    \
    const u16* vbase_ = vt_bh + (kt_) * 64;                                   \
    _Pragma("unroll")                                                         \
    for (int p = 0; p < 2; ++p) {                                             \
      int s_ = p * 256 + tid;                                                 \
      int row_ = s_ >> 3;                                                     \
      int c8_ = (s_ & 7) ^ (row_ & 7);                                        \
      int krow_ = (row_ & 0x23) | ((row_ & 0x0C) << 1) | ((row_ & 0x10) >> 2);\
      cp16(kbase_ + krow_ * 64 + c8_ * 8, &Ksm[b_][(p * 256 + w * 64) * 8]);  \
      cp16(vbase_ + (size_t)row_ * TSEQ + c8_ * 8,                            \
           &Vsm[b_][(p * 256 + w * 64) * 8]);                                 \
    }                                                                         \
  } while (0)

  STAGE(0, 0);

  for (int kt = 0; kt < nk; ++kt) {
    // barrier 1: all waves finished READING buf((kt+1)&1) in iter kt-1
    asm volatile("s_barrier" ::: "memory");
    if (kt + 1 < nk) {
      STAGE(kt + 1, (kt + 1) & 1);               // DMA for kt+1 (stays in flight)
      asm volatile("s_waitcnt vmcnt(4)" ::: "memory");  // tile kt landed
    } else {
      asm volatile("s_waitcnt vmcnt(0)" ::: "memory");  // last tile: drain
    }
    // barrier 2: all waves' tile-kt DMA landed
    asm volatile("s_barrier" ::: "memory");

    const u16* Kb = Ksm[kt & 1];
    const u16* Vb = Vsm[kt & 1];

    __builtin_amdgcn_s_setprio(1);
#pragma unroll
    for (int mi = 0; mi < 2; ++mi) {
      const int qmin = qbase + mi * 64 + w * 16;
      if (kt * 64 > qmin + 15) continue;   // whole fragment masked
      const int qlane = qmin + l16;

      // S^T = K Q^T : lane (quad,l16) gets S[q=l16][kappa(j*16+quad*4+r)]
      f32x4 s[4];
#pragma unroll
      for (int j = 0; j < 4; ++j) {
        int row = j * 16 + l16;
        int ca = quad ^ (row & 7);
        int cb = (4 + quad) ^ (row & 7);
        short8 k0 = *(const short8*)(Kb + row * 64 + ca * 8);
        short8 k1 = *(const short8*)(Kb + row * 64 + cb * 8);
        f32x4 z = (f32x4){0.f, 0.f, 0.f, 0.f};
        z = mfma16(k0, qf[mi][0], z);
        z = mfma16(k1, qf[mi][1], z);
        s[j] = z;
      }
      if (kt * 64 + 63 > qmin) {  // diagonal overlap: elementwise causal mask
#pragma unroll
        for (int j = 0; j < 4; ++j) {
#pragma unroll
          for (int r = 0; r < 4; ++r) {
            int kabs = kt * 64 + ((j >> 1) << 5) + (quad << 3) + ((j & 1) << 2) + r;
            if (kabs > qlane) s[j][r] = -1e30f;
          }
        }
      }
      // static-max softmax: p = exp2(s*cexp - M); pack straight into the
      // PV A-operand fragments (keys already lane-local in k-slot order).
      short8 ap0, ap1;
#pragma unroll
      for (int j = 0; j < 4; ++j) {
#pragma unroll
        for (int r = 0; r < 4; ++r) {
          float p_ = __builtin_amdgcn_exp2f(__builtin_fmaf(s[j][r], cexp, -M));
          lp[mi] += p_;
          u16 pb = f2b(p_);
          if (j < 2) ap0[j * 4 + r] = (short)pb;
          else       ap1[(j - 2) * 4 + r] = (short)pb;
        }
      }
      // O += P V : A = P (rows q=l16, k = quad*8+e), B = V^T (cols d=l16)
#pragma unroll
      for (int j = 0; j < 4; ++j) {
        int row = j * 16 + l16;  // d
        int ca = quad ^ (row & 7);
        int cb = (4 + quad) ^ (row & 7);
        short8 v0 = *(const short8*)(Vb + row * 64 + ca * 8);
        short8 v1 = *(const short8*)(Vb + row * 64 + cb * 8);
        o[mi][j] = mfma16(ap0, v0, o[mi][j]);
        o[mi][j] = mfma16(ap1, v1, o[mi][j]);
      }
    }
    __builtin_amdgcn_s_setprio(0);
  }
#undef STAGE

  // epilogue: full softmax denominator = sum of lp across the 4 quads
  // (lane (quad,l16) holds the partial for q=l16 over keys quad*8+e, +32).
#pragma unroll
  for (int mi = 0; mi < 2; ++mi) {
    lp[mi] += __shfl_xor(lp[mi], 16);
    lp[mi] += __shfl_xor(lp[mi], 32);
  }
  const int b_ = bh >> 4, h = bh & 15;
#pragma unroll
  for (int mi = 0; mi < 2; ++mi) {
    float dn[4];
#pragma unroll
    for (int r = 0; r < 4; ++r)
      dn[r] = __shfl(lp[mi], (lane & 48) + quad * 4 + r);  // denom for q-row quad*4+r
#pragma unroll
    for (int j = 0; j < 4; ++j)
#pragma unroll
      for (int r = 0; r < 4; ++r) {
        int t = qbase + mi * 64 + w * 16 + quad * 4 + r;
        int d = j * 16 + l16;
        ob[((size_t)(b_ * TSEQ + t)) * 1024 + h * 64 + d] =
            f2b(o[mi][j][r] / dn[r]);
      }
  }
}

// ------------------------------------------------------- out GEMM (fp32 out)
// Grid (8,64) = 512 blocks. XCD chunk = 8 m-panels x 8 n-tiles: A 2MB +
// B 2MB = 4MB = exact per-XCD L2 fit.
__global__ __launch_bounds__(256) void gemm_out_kernel(
    const u16* __restrict__ attn, const u16* __restrict__ Wt,
    const float* __restrict__ bias, float* __restrict__ out) {
  __shared__ __align__(16) u16 Asm[2 * 4096];
  __shared__ __align__(16) u16 Bsm[2 * 4096];
  f32x4 acc[4][4];
  const int flat = blockIdx.y * 8 + blockIdx.x;
  const int swz = (flat & 7) * 64 + (flat >> 3);    // bijective (512%8==0)
  const int m0 = (swz >> 3) * 128;
  const int n0 = (swz & 7) * 128;
  gemm128_pipe(attn, Wt, m0, n0, Asm, Bsm, acc);

  const int tid = threadIdx.x;
  const int w = tid >> 6, lane = tid & 63, quad = lane >> 4, l16 = lane & 15;
  const int wm = (w >> 1) * 64, wn = (w & 1) * 64;
#pragma unroll
  for (int j = 0; j < 4; ++j) {
    int col = n0 + wn + j * 16 + l16;
    float bv = bias[col];
#pragma unroll
    for (int i = 0; i < 4; ++i)
#pragma unroll
      for (int r = 0; r < 4; ++r) {
        int m = m0 + wm + i * 16 + quad * 4 + r;
        out[(size_t)m * 1024 + col] = acc[i][j][r] + bv;
      }
  }
}

// ---------------------------------------------------------------- launcher
extern "C" void kernel_launch(void* const* d_in, const int* in_sizes, int n_in,
                              void* d_out, int out_size, void* d_ws, size_t ws_size,
                              hipStream_t stream) {
  const float* x    = (const float*)d_in[0];   // [8192][1024] fp32
  const float* Wqkv = (const float*)d_in[1];   // [1024][3072] fp32
  const float* bqkv = (const float*)d_in[2];   // [3072] fp32
  const float* Wout = (const float*)d_in[3];   // [1024][1024] fp32
  const float* bout = (const float*)d_in[4];   // [1024] fp32
  float* out = (float*)d_out;                  // [8192][1024] fp32

  u16* ws = (u16*)d_ws;
  u16* xb     = ws;                                  // 8M   bf16 x
  u16* wqkv_t = xb + (size_t)MROWS * 1024;           // 3M   [3072][1024]
  u16* wout_t = wqkv_t + (size_t)N3 * 1024;          // 1M   [1024][1024]
  u16* qbuf   = wout_t + (size_t)1024 * 1024;        // 8M   [bh][t][d]
  u16* kbuf   = qbuf + (size_t)MROWS * 1024;         // 8M   [bh][t][d]
  u16* vtbuf  = kbuf + (size_t)MROWS * 1024;         // 8M   [bh][d][t]
  u16* obuf   = vtbuf + (size_t)MROWS * 1024;        // 8M   [b][t][c]
  (void)ws_size; (void)n_in; (void)in_sizes; (void)out_size;

  prep_kernel<<<PREP_TOTAL, 256, 0, stream>>>(x, xb, Wqkv, wqkv_t, Wout, wout_t);
  gemm_qkv_kernel<<<dim3(24, 64), 256, 0, stream>>>(xb, wqkv_t, bqkv, qbuf, kbuf, vtbuf);
  attn_kernel<<<dim3(TSEQ / 128, BATCH * N_HEADS), 256, 0, stream>>>(qbuf, kbuf, vtbuf, obuf);
  gemm_out_kernel<<<dim3(8, 64), 256, 0, stream>>>(obuf, wout_t, bout, out);
}

// Round 8
// 278.607 us; speedup vs baseline: 1.1146x; 1.1146x over previous
//
#include <hip/hip_runtime.h>
#include <hip/hip_bf16.h>

// CausalSelfAttention on gfx950 — round 14.
// r13 post-mortem: qkv XCD m-chunked swizzle regressed 94->114us DESPITE
// FETCH 71.8->57.5MB (prediction matched on counter, wrong on mechanism):
// at 16% HBM we're latency-bound, and m-chunking gives every XCD the full
// 6MB B > 4MB L2 -> B thrashes L2 continuously (before, dispatch-order
// y-bands kept active B panels hot). Fifth failed excursion from r11.
// r14: (1) qkv swizzle reverted to flat r11 mapping (94us twice-measured);
// (2) qkv v-epilogue packs 4 consecutive-t stores into one short4 (which==2
// is block-uniform; 64 -> 16 stores on 1/3 of blocks); (3) attn/out/prep
// kept exactly as r13 (remainder was -3.3us vs r11).

typedef unsigned short u16;
typedef __attribute__((ext_vector_type(8))) short short8;
typedef __attribute__((ext_vector_type(4))) short short4v;
typedef __attribute__((ext_vector_type(4))) float f32x4;

#define N_HEADS 16
#define HEAD_DIM 64
#define TSEQ 2048
#define BATCH 4
#define MROWS (BATCH * TSEQ)   // 8192
#define N3 3072                // 3*D_MODEL

__device__ __forceinline__ void cp16(const u16* g, u16* l) {
  __builtin_amdgcn_global_load_lds((const __attribute__((address_space(1))) void*)g,
                                   (__attribute__((address_space(3))) void*)l, 16, 0, 0);
}

__device__ __forceinline__ f32x4 mfma16(short8 a, short8 b, f32x4 c) {
  return __builtin_amdgcn_mfma_f32_16x16x32_bf16(a, b, c, 0, 0, 0);
}

__device__ __forceinline__ u16 f2b(float f) {
  __hip_bfloat16 h = __float2bfloat16(f);
  return *reinterpret_cast<u16*>(&h);
}

// ---------------------------------------------------- fused prep kernel
#define PREP_CVT_BLOCKS 8192
#define PREP_WQKV_BLOCKS (96 * 32)
#define PREP_WOUT_BLOCKS (32 * 32)
#define PREP_TOTAL (PREP_CVT_BLOCKS + PREP_WQKV_BLOCKS + PREP_WOUT_BLOCKS)

__device__ __forceinline__ void transpose_tile(const float* __restrict__ src,
                                               u16* __restrict__ dst,
                                               int R, int Cn, int c0, int r0,
                                               float (*tile)[33]) {
  const int tx = threadIdx.x & 31, ty = threadIdx.x >> 5;
  for (int i = ty; i < 32; i += 8)
    tile[i][tx] = src[(size_t)(r0 + i) * Cn + c0 + tx];
  __syncthreads();
  for (int i = ty; i < 32; i += 8)
    dst[(size_t)(c0 + i) * R + r0 + tx] = f2b(tile[tx][i]);
}

__global__ __launch_bounds__(256) void prep_kernel(
    const float* __restrict__ x, u16* __restrict__ xb,
    const float* __restrict__ Wqkv, u16* __restrict__ wqkv_t,
    const float* __restrict__ Wout, u16* __restrict__ wout_t) {
  __shared__ float tile[32][33];
  const int bx = blockIdx.x;
  if (bx < PREP_CVT_BLOCKS) {
    int i = bx * 256 + threadIdx.x;            // n4 = 8192*256 exactly
    float4 v = *(const float4*)(x + (size_t)i * 4);
    u16* d = xb + (size_t)i * 4;
    d[0] = f2b(v.x); d[1] = f2b(v.y); d[2] = f2b(v.z); d[3] = f2b(v.w);
  } else if (bx < PREP_CVT_BLOCKS + PREP_WQKV_BLOCKS) {
    int b2 = bx - PREP_CVT_BLOCKS;
    int c0 = (b2 % 96) * 32, r0 = (b2 / 96) * 32;
    transpose_tile(Wqkv, wqkv_t, 1024, N3, c0, r0, tile);
  } else {
    int b3 = bx - PREP_CVT_BLOCKS - PREP_WQKV_BLOCKS;
    int c0 = (b3 % 32) * 32, r0 = (b3 / 32) * 32;
    transpose_tile(Wout, wout_t, 1024, 1024, c0, r0, tile);
  }
}

// ------------------------------------------ 128^2 GEMM core, SYNC variant
// r8/r11-measured 94us / MfmaUtil 22.7 on gemm_qkv. Single 16KiB LDS,
// __syncthreads-drained staging, BK=32, max occupancy. Do NOT pipeline,
// grow LDS, or m-chunk-swizzle (r9/r10/r12/r13 all regressed).
__device__ __forceinline__ void gemm128_sync(const u16* __restrict__ A,
                                             const u16* __restrict__ Bt,
                                             int m0, int n0,
                                             u16* Asm, u16* Bsm,
                                             f32x4 acc[4][4]) {
  const int tid = threadIdx.x;
  const int w = tid >> 6;
  const int lane = tid & 63;
  const int quad = lane >> 4;
  const int l16 = lane & 15;
  const int wm = (w >> 1) * 64;
  const int wn = (w & 1) * 64;

#pragma unroll
  for (int i = 0; i < 4; ++i)
#pragma unroll
    for (int j = 0; j < 4; ++j) acc[i][j] = (f32x4){0.f, 0.f, 0.f, 0.f};

  for (int k0 = 0; k0 < 1024; k0 += 32) {
    __syncthreads();
#pragma unroll
    for (int p = 0; p < 2; ++p) {
      int s = p * 256 + tid;
      int row = s >> 2;
      int c4 = (s & 3) ^ ((row >> 1) & 3);
      cp16(A + (size_t)(m0 + row) * 1024 + k0 + c4 * 8,
           Asm + (size_t)(p * 256 + w * 64) * 8);
      cp16(Bt + (size_t)(n0 + row) * 1024 + k0 + c4 * 8,
           Bsm + (size_t)(p * 256 + w * 64) * 8);
    }
    __syncthreads();

    short8 a[4], b[4];
#pragma unroll
    for (int i = 0; i < 4; ++i) {
      int row = wm + i * 16 + l16;
      int c4 = quad ^ ((row >> 1) & 3);
      a[i] = *(const short8*)(Asm + row * 32 + c4 * 8);
    }
#pragma unroll
    for (int j = 0; j < 4; ++j) {
      int row = wn + j * 16 + l16;
      int c4 = quad ^ ((row >> 1) & 3);
      b[j] = *(const short8*)(Bsm + row * 32 + c4 * 8);
    }
#pragma unroll
    for (int i = 0; i < 4; ++i)
#pragma unroll
      for (int j = 0; j < 4; ++j)
        acc[i][j] = mfma16(a[i], b[j], acc[i][j]);
  }
}

// -------------------------------------------- 128^2 GEMM core, pipelined
// Kept for gemm_out only (r10/r11 config; untouched).
__device__ __forceinline__ void gemm128_pipe(const u16* __restrict__ A,
                                             const u16* __restrict__ Bt,
                                             int m0, int n0,
                                             u16* Asm, u16* Bsm,
                                             f32x4 acc[4][4]) {
  const int tid = threadIdx.x;
  const int w = tid >> 6;
  const int lane = tid & 63;
  const int quad = lane >> 4;
  const int l16 = lane & 15;
  const int wm = (w >> 1) * 64;
  const int wn = (w & 1) * 64;

#pragma unroll
  for (int i = 0; i < 4; ++i)
#pragma unroll
    for (int j = 0; j < 4; ++j) acc[i][j] = (f32x4){0.f, 0.f, 0.f, 0.f};

#define STG128(k0_, b_)                                                     \
  do {                                                                      \
    _Pragma("unroll")                                                       \
    for (int p = 0; p < 2; ++p) {                                           \
      int s = p * 256 + tid;                                                \
      int row = s >> 2;                                                     \
      int c4 = (s & 3) ^ ((row >> 1) & 3);                                  \
      cp16(A + (size_t)(m0 + row) * 1024 + (k0_) + c4 * 8,                  \
           Asm + (size_t)(b_) * 4096 + (p * 256 + w * 64) * 8);             \
      cp16(Bt + (size_t)(n0 + row) * 1024 + (k0_) + c4 * 8,                 \
           Bsm + (size_t)(b_) * 4096 + (p * 256 + w * 64) * 8);             \
    }                                                                       \
  } while (0)

  STG128(0, 0);
  STG128(32, 1);
  asm volatile("s_waitcnt vmcnt(4)" ::: "memory");  // tile 0 landed
  asm volatile("s_barrier" ::: "memory");

  for (int kt = 0; kt < 32; ++kt) {
    const u16* Ab = Asm + (kt & 1) * 4096;
    const u16* Bb = Bsm + (kt & 1) * 4096;
    short8 a[4], b[4];
#pragma unroll
    for (int i = 0; i < 4; ++i) {
      int row = wm + i * 16 + l16;
      int c4 = quad ^ ((row >> 1) & 3);
      a[i] = *(const short8*)(Ab + row * 32 + c4 * 8);
    }
#pragma unroll
    for (int j = 0; j < 4; ++j) {
      int row = wn + j * 16 + l16;
      int c4 = quad ^ ((row >> 1) & 3);
      b[j] = *(const short8*)(Bb + row * 32 + c4 * 8);
    }
#pragma unroll
    for (int i = 0; i < 4; ++i)
#pragma unroll
      for (int j = 0; j < 4; ++j)
        acc[i][j] = mfma16(a[i], b[j], acc[i][j]);

    asm volatile("s_barrier" ::: "memory");  // all waves done reading buf
    if (kt + 2 < 32) {
      STG128((kt + 2) * 32, kt & 1);         // into freed buf; stays in flight
      asm volatile("s_waitcnt vmcnt(4)" ::: "memory");  // tile kt+1 landed
    } else if (kt + 1 < 32) {
      asm volatile("s_waitcnt vmcnt(0)" ::: "memory");  // last tile: drain
    }
    asm volatile("s_barrier" ::: "memory");  // buf(kt+1) ready for all waves
  }
#undef STG128
}

// ---------------------------------------------------------------- QKV GEMM
// Flat mapping (r11). v-blocks (which==2, block-uniform) pack the 4
// consecutive-t stores into one aligned short4.
__global__ __launch_bounds__(256) void gemm_qkv_kernel(
    const u16* __restrict__ x, const u16* __restrict__ Wt,
    const float* __restrict__ bias,
    u16* __restrict__ qb, u16* __restrict__ kb, u16* __restrict__ vtb) {
  __shared__ __align__(16) u16 Asm[128 * 32];
  __shared__ __align__(16) u16 Bsm[128 * 32];
  f32x4 acc[4][4];
  const int m0 = blockIdx.y * 128;
  const int n0 = blockIdx.x * 128;
  gemm128_sync(x, Wt, m0, n0, Asm, Bsm, acc);

  const int tid = threadIdx.x;
  const int w = tid >> 6, lane = tid & 63, quad = lane >> 4, l16 = lane & 15;
  const int wm = (w >> 1) * 64, wn = (w & 1) * 64;
#pragma unroll
  for (int j = 0; j < 4; ++j) {
    int col = n0 + wn + j * 16 + l16;
    float bv = bias[col];
    int which = col >> 10;     // 0=q 1=k 2=v (block-uniform)
    int rem = col & 1023;
    int h = rem >> 6, d = rem & 63;
#pragma unroll
    for (int i = 0; i < 4; ++i) {
      int m4 = m0 + wm + i * 16 + quad * 4;    // aligned 4, within one seq
      int b_ = m4 >> 11, t4 = m4 & 2047;
      int bh = b_ * N_HEADS + h;
      if (which == 2) {
        short4v pk;
#pragma unroll
        for (int r = 0; r < 4; ++r) pk[r] = (short)f2b(acc[i][j][r] + bv);
        *(short4v*)(vtb + ((size_t)((bh << 6) + d)) * TSEQ + t4) = pk;
      } else {
        u16* dst = (which == 0) ? qb : kb;
#pragma unroll
        for (int r = 0; r < 4; ++r)
          dst[((size_t)(bh * TSEQ + t4 + r) << 6) + d] = f2b(acc[i][j][r] + bv);
      }
    }
  }
}

// ---------------------------------------------------------------- attention
// Swapped QK^T + bit-permuted K staging; P in-register (see r8 header).
// XCD-chunked swizzle (8 bh x 16 qt per XCD = K/V 4MB L2 fit) + setprio(1)
// around per-mi compute (T5) — kept from r13 (remainder -3.3us vs r11).
__global__ __launch_bounds__(256, 5) void attn_kernel(const u16* __restrict__ qb,
                                                      const u16* __restrict__ kb,
                                                      const u16* __restrict__ vtb,
                                                      u16* __restrict__ ob) {
  const int flat = blockIdx.y * 16 + blockIdx.x;
  const int swz = (flat & 7) * 128 + (flat >> 3);   // bijective (1024%8==0)
  const int bh = swz >> 4;                          // 0..63
  const int qt = 15 - (swz & 15);                   // 15..0 heavy-first
  __shared__ __align__(16) u16 Ksm[2][4096];     // [buf][rho 64][d 64] swizzled
  __shared__ __align__(16) u16 Vsm[2][4096];     // [buf][d 64][t_k 64] swizzled
  const int tid = threadIdx.x;
  const int w = tid >> 6, lane = tid & 63, quad = lane >> 4, l16 = lane & 15;
  const int qbase = qt * 128;

  // Q fragments (B-operand layout == A-layout for 16x16x32), in registers
  short8 qf[2][2];
#pragma unroll
  for (int mi = 0; mi < 2; ++mi) {
    const u16* qr = qb + ((size_t)(bh * TSEQ + qbase + mi * 64 + w * 16 + l16)) * 64;
    qf[mi][0] = *(const short8*)(qr + quad * 8);
    qf[mi][1] = *(const short8*)(qr + 32 + quad * 8);
  }

  f32x4 o[2][4];
  float lp[2] = {0.f, 0.f};
#pragma unroll
  for (int mi = 0; mi < 2; ++mi)
#pragma unroll
    for (int j = 0; j < 4; ++j) o[mi][j] = (f32x4){0.f, 0.f, 0.f, 0.f};
  const float cexp = 0.18033688011112042f;  // (1/sqrt(64)) * log2(e)
  const float M = 10.0f;                    // static softmax shift

  const u16* kb_bh = kb + (size_t)bh * TSEQ * 64;
  const u16* vt_bh = vtb + (size_t)bh * 64 * TSEQ;
  const int nk = 2 * qt + 2;

  // stage k-tile kt into buffer b: 4 DMA issues per thread (vmcnt +=4).
  // K rows bit-permuted: LDS row rho <- key kappa(rho); V rows natural (d).
#define STAGE(kt_, b_)                                                        \
  do {                                                                        \
    const u16* kbase_ = kb_bh + (size_t)((kt_) * 64) * 64;                    \
    const u16* vbase_ = vt_bh + (kt_) * 64;                                   \
    _Pragma("unroll")                                                         \
    for (int p = 0; p < 2; ++p) {                                             \
      int s_ = p * 256 + tid;                                                 \
      int row_ = s_ >> 3;                                                     \
      int c8_ = (s_ & 7) ^ (row_ & 7);                                        \
      int krow_ = (row_ & 0x23) | ((row_ & 0x0C) << 1) | ((row_ & 0x10) >> 2);\
      cp16(kbase_ + krow_ * 64 + c8_ * 8, &Ksm[b_][(p * 256 + w * 64) * 8]);  \
      cp16(vbase_ + (size_t)row_ * TSEQ + c8_ * 8,                            \
           &Vsm[b_][(p * 256 + w * 64) * 8]);                                 \
    }                                                                         \
  } while (0)

  STAGE(0, 0);

  for (int kt = 0; kt < nk; ++kt) {
    // barrier 1: all waves finished READING buf((kt+1)&1) in iter kt-1
    asm volatile("s_barrier" ::: "memory");
    if (kt + 1 < nk) {
      STAGE(kt + 1, (kt + 1) & 1);               // DMA for kt+1 (stays in flight)
      asm volatile("s_waitcnt vmcnt(4)" ::: "memory");  // tile kt landed
    } else {
      asm volatile("s_waitcnt vmcnt(0)" ::: "memory");  // last tile: drain
    }
    // barrier 2: all waves' tile-kt DMA landed
    asm volatile("s_barrier" ::: "memory");

    const u16* Kb = Ksm[kt & 1];
    const u16* Vb = Vsm[kt & 1];

    __builtin_amdgcn_s_setprio(1);
#pragma unroll
    for (int mi = 0; mi < 2; ++mi) {
      const int qmin = qbase + mi * 64 + w * 16;
      if (kt * 64 > qmin + 15) continue;   // whole fragment masked
      const int qlane = qmin + l16;

      // S^T = K Q^T : lane (quad,l16) gets S[q=l16][kappa(j*16+quad*4+r)]
      f32x4 s[4];
#pragma unroll
      for (int j = 0; j < 4; ++j) {
        int row = j * 16 + l16;
        int ca = quad ^ (row & 7);
        int cb = (4 + quad) ^ (row & 7);
        short8 k0 = *(const short8*)(Kb + row * 64 + ca * 8);
        short8 k1 = *(const short8*)(Kb + row * 64 + cb * 8);
        f32x4 z = (f32x4){0.f, 0.f, 0.f, 0.f};
        z = mfma16(k0, qf[mi][0], z);
        z = mfma16(k1, qf[mi][1], z);
        s[j] = z;
      }
      if (kt * 64 + 63 > qmin) {  // diagonal overlap: elementwise causal mask
#pragma unroll
        for (int j = 0; j < 4; ++j) {
#pragma unroll
          for (int r = 0; r < 4; ++r) {
            int kabs = kt * 64 + ((j >> 1) << 5) + (quad << 3) + ((j & 1) << 2) + r;
            if (kabs > qlane) s[j][r] = -1e30f;
          }
        }
      }
      // static-max softmax: p = exp2(s*cexp - M); pack straight into the
      // PV A-operand fragments (keys already lane-local in k-slot order).
      short8 ap0, ap1;
#pragma unroll
      for (int j = 0; j < 4; ++j) {
#pragma unroll
        for (int r = 0; r < 4; ++r) {
          float p_ = __builtin_amdgcn_exp2f(__builtin_fmaf(s[j][r], cexp, -M));
          lp[mi] += p_;
          u16 pb = f2b(p_);
          if (j < 2) ap0[j * 4 + r] = (short)pb;
          else       ap1[(j - 2) * 4 + r] = (short)pb;
        }
      }
      // O += P V : A = P (rows q=l16, k = quad*8+e), B = V^T (cols d=l16)
#pragma unroll
      for (int j = 0; j < 4; ++j) {
        int row = j * 16 + l16;  // d
        int ca = quad ^ (row & 7);
        int cb = (4 + quad) ^ (row & 7);
        short8 v0 = *(const short8*)(Vb + row * 64 + ca * 8);
        short8 v1 = *(const short8*)(Vb + row * 64 + cb * 8);
        o[mi][j] = mfma16(ap0, v0, o[mi][j]);
        o[mi][j] = mfma16(ap1, v1, o[mi][j]);
      }
    }
    __builtin_amdgcn_s_setprio(0);
  }
#undef STAGE

  // epilogue: full softmax denominator = sum of lp across the 4 quads
  // (lane (quad,l16) holds the partial for q=l16 over keys quad*8+e, +32).
#pragma unroll
  for (int mi = 0; mi < 2; ++mi) {
    lp[mi] += __shfl_xor(lp[mi], 16);
    lp[mi] += __shfl_xor(lp[mi], 32);
  }
  const int b_ = bh >> 4, h = bh & 15;
#pragma unroll
  for (int mi = 0; mi < 2; ++mi) {
    float dn[4];
#pragma unroll
    for (int r = 0; r < 4; ++r)
      dn[r] = __shfl(lp[mi], (lane & 48) + quad * 4 + r);  // denom for q-row quad*4+r
#pragma unroll
    for (int j = 0; j < 4; ++j)
#pragma unroll
      for (int r = 0; r < 4; ++r) {
        int t = qbase + mi * 64 + w * 16 + quad * 4 + r;
        int d = j * 16 + l16;
        ob[((size_t)(b_ * TSEQ + t)) * 1024 + h * 64 + d] =
            f2b(o[mi][j][r] / dn[r]);
      }
  }
}

// ------------------------------------------------------- out GEMM (fp32 out)
// Grid (8,64) = 512 blocks. XCD chunk = 8 m-panels x 8 n-tiles: A 2MB +
// B 2MB = 4MB L2 fit (kept from r13).
__global__ __launch_bounds__(256) void gemm_out_kernel(
    const u16* __restrict__ attn, const u16* __restrict__ Wt,
    const float* __restrict__ bias, float* __restrict__ out) {
  __shared__ __align__(16) u16 Asm[2 * 4096];
  __shared__ __align__(16) u16 Bsm[2 * 4096];
  f32x4 acc[4][4];
  const int flat = blockIdx.y * 8 + blockIdx.x;
  const int swz = (flat & 7) * 64 + (flat >> 3);    // bijective (512%8==0)
  const int m0 = (swz >> 3) * 128;
  const int n0 = (swz & 7) * 128;
  gemm128_pipe(attn, Wt, m0, n0, Asm, Bsm, acc);

  const int tid = threadIdx.x;
  const int w = tid >> 6, lane = tid & 63, quad = lane >> 4, l16 = lane & 15;
  const int wm = (w >> 1) * 64, wn = (w & 1) * 64;
#pragma unroll
  for (int j = 0; j < 4; ++j) {
    int col = n0 + wn + j * 16 + l16;
    float bv = bias[col];
#pragma unroll
    for (int i = 0; i < 4; ++i)
#pragma unroll
      for (int r = 0; r < 4; ++r) {
        int m = m0 + wm + i * 16 + quad * 4 + r;
        out[(size_t)m * 1024 + col] = acc[i][j][r] + bv;
      }
  }
}

// ---------------------------------------------------------------- launcher
extern "C" void kernel_launch(void* const* d_in, const int* in_sizes, int n_in,
                              void* d_out, int out_size, void* d_ws, size_t ws_size,
                              hipStream_t stream) {
  const float* x    = (const float*)d_in[0];   // [8192][1024] fp32
  const float* Wqkv = (const float*)d_in[1];   // [1024][3072] fp32
  const float* bqkv = (const float*)d_in[2];   // [3072] fp32
  const float* Wout = (const float*)d_in[3];   // [1024][1024] fp32
  const float* bout = (const float*)d_in[4];   // [1024] fp32
  float* out = (float*)d_out;                  // [8192][1024] fp32

  u16* ws = (u16*)d_ws;
  u16* xb     = ws;                                  // 8M   bf16 x
  u16* wqkv_t = xb + (size_t)MROWS * 1024;           // 3M   [3072][1024]
  u16* wout_t = wqkv_t + (size_t)N3 * 1024;          // 1M   [1024][1024]
  u16* qbuf   = wout_t + (size_t)1024 * 1024;        // 8M   [bh][t][d]
  u16* kbuf   = qbuf + (size_t)MROWS * 1024;         // 8M   [bh][t][d]
  u16* vtbuf  = kbuf + (size_t)MROWS * 1024;         // 8M   [bh][d][t]
  u16* obuf   = vtbuf + (size_t)MROWS * 1024;        // 8M   [b][t][c]
  (void)ws_size; (void)n_in; (void)in_sizes; (void)out_size;

  prep_kernel<<<PREP_TOTAL, 256, 0, stream>>>(x, xb, Wqkv, wqkv_t, Wout, wout_t);
  gemm_qkv_kernel<<<dim3(N3 / 128, MROWS / 128), 256, 0, stream>>>(xb, wqkv_t, bqkv, qbuf, kbuf, vtbuf);
  attn_kernel<<<dim3(TSEQ / 128, BATCH * N_HEADS), 256, 0, stream>>>(qbuf, kbuf, vtbuf, obuf);
  gemm_out_kernel<<<dim3(8, 64), 256, 0, stream>>>(obuf, wout_t, bout, out);
}

// Round 9
// 252.229 us; speedup vs baseline: 1.2312x; 1.1046x over previous
//
#include <hip/hip_runtime.h>
#include <hip/hip_bf16.h>

// CausalSelfAttention on gfx950 — round 15.
// r14: 278.6us best; qkv off the top-5 (v-pack + flat mapping). attn now #1
// at 103us: MfmaUtil 13.8 / VALU 26.4 / HBM 6.9 / Occ 22.4 — latency-bound,
// occupancy-limited: 1024 blocks x 4 waves = 16 waves/CU resident vs 32
// slots. r15: attn 4 waves x 2 frags -> 8 waves x 1 frag (512 thr), same
// 128-row tile, same LDS (32KB, 4 blocks/CU = 32 waves = full), same
// barrier+vmcnt pipeline (now vmcnt(2): 1 K + 1 V cp16 per thread).
// launch_bounds(512,8) caps VGPR at 64 (per-wave state halved, fits).
// qkv/out/prep untouched.

typedef unsigned short u16;
typedef __attribute__((ext_vector_type(8))) short short8;
typedef __attribute__((ext_vector_type(4))) short short4v;
typedef __attribute__((ext_vector_type(4))) float f32x4;

#define N_HEADS 16
#define HEAD_DIM 64
#define TSEQ 2048
#define BATCH 4
#define MROWS (BATCH * TSEQ)   // 8192
#define N3 3072                // 3*D_MODEL

__device__ __forceinline__ void cp16(const u16* g, u16* l) {
  __builtin_amdgcn_global_load_lds((const __attribute__((address_space(1))) void*)g,
                                   (__attribute__((address_space(3))) void*)l, 16, 0, 0);
}

__device__ __forceinline__ f32x4 mfma16(short8 a, short8 b, f32x4 c) {
  return __builtin_amdgcn_mfma_f32_16x16x32_bf16(a, b, c, 0, 0, 0);
}

__device__ __forceinline__ u16 f2b(float f) {
  __hip_bfloat16 h = __float2bfloat16(f);
  return *reinterpret_cast<u16*>(&h);
}

// ---------------------------------------------------- fused prep kernel
#define PREP_CVT_BLOCKS 8192
#define PREP_WQKV_BLOCKS (96 * 32)
#define PREP_WOUT_BLOCKS (32 * 32)
#define PREP_TOTAL (PREP_CVT_BLOCKS + PREP_WQKV_BLOCKS + PREP_WOUT_BLOCKS)

__device__ __forceinline__ void transpose_tile(const float* __restrict__ src,
                                               u16* __restrict__ dst,
                                               int R, int Cn, int c0, int r0,
                                               float (*tile)[33]) {
  const int tx = threadIdx.x & 31, ty = threadIdx.x >> 5;
  for (int i = ty; i < 32; i += 8)
    tile[i][tx] = src[(size_t)(r0 + i) * Cn + c0 + tx];
  __syncthreads();
  for (int i = ty; i < 32; i += 8)
    dst[(size_t)(c0 + i) * R + r0 + tx] = f2b(tile[tx][i]);
}

__global__ __launch_bounds__(256) void prep_kernel(
    const float* __restrict__ x, u16* __restrict__ xb,
    const float* __restrict__ Wqkv, u16* __restrict__ wqkv_t,
    const float* __restrict__ Wout, u16* __restrict__ wout_t) {
  __shared__ float tile[32][33];
  const int bx = blockIdx.x;
  if (bx < PREP_CVT_BLOCKS) {
    int i = bx * 256 + threadIdx.x;            // n4 = 8192*256 exactly
    float4 v = *(const float4*)(x + (size_t)i * 4);
    u16* d = xb + (size_t)i * 4;
    d[0] = f2b(v.x); d[1] = f2b(v.y); d[2] = f2b(v.z); d[3] = f2b(v.w);
  } else if (bx < PREP_CVT_BLOCKS + PREP_WQKV_BLOCKS) {
    int b2 = bx - PREP_CVT_BLOCKS;
    int c0 = (b2 % 96) * 32, r0 = (b2 / 96) * 32;
    transpose_tile(Wqkv, wqkv_t, 1024, N3, c0, r0, tile);
  } else {
    int b3 = bx - PREP_CVT_BLOCKS - PREP_WQKV_BLOCKS;
    int c0 = (b3 % 32) * 32, r0 = (b3 / 32) * 32;
    transpose_tile(Wout, wout_t, 1024, 1024, c0, r0, tile);
  }
}

// ------------------------------------------ 128^2 GEMM core, SYNC variant
// r8/r11-measured 94us / MfmaUtil 22.7 on gemm_qkv. Single 16KiB LDS,
// __syncthreads-drained staging, BK=32, max occupancy. Do NOT pipeline,
// grow LDS, or m-chunk-swizzle (r9/r10/r12/r13 all regressed).
__device__ __forceinline__ void gemm128_sync(const u16* __restrict__ A,
                                             const u16* __restrict__ Bt,
                                             int m0, int n0,
                                             u16* Asm, u16* Bsm,
                                             f32x4 acc[4][4]) {
  const int tid = threadIdx.x;
  const int w = tid >> 6;
  const int lane = tid & 63;
  const int quad = lane >> 4;
  const int l16 = lane & 15;
  const int wm = (w >> 1) * 64;
  const int wn = (w & 1) * 64;

#pragma unroll
  for (int i = 0; i < 4; ++i)
#pragma unroll
    for (int j = 0; j < 4; ++j) acc[i][j] = (f32x4){0.f, 0.f, 0.f, 0.f};

  for (int k0 = 0; k0 < 1024; k0 += 32) {
    __syncthreads();
#pragma unroll
    for (int p = 0; p < 2; ++p) {
      int s = p * 256 + tid;
      int row = s >> 2;
      int c4 = (s & 3) ^ ((row >> 1) & 3);
      cp16(A + (size_t)(m0 + row) * 1024 + k0 + c4 * 8,
           Asm + (size_t)(p * 256 + w * 64) * 8);
      cp16(Bt + (size_t)(n0 + row) * 1024 + k0 + c4 * 8,
           Bsm + (size_t)(p * 256 + w * 64) * 8);
    }
    __syncthreads();

    short8 a[4], b[4];
#pragma unroll
    for (int i = 0; i < 4; ++i) {
      int row = wm + i * 16 + l16;
      int c4 = quad ^ ((row >> 1) & 3);
      a[i] = *(const short8*)(Asm + row * 32 + c4 * 8);
    }
#pragma unroll
    for (int j = 0; j < 4; ++j) {
      int row = wn + j * 16 + l16;
      int c4 = quad ^ ((row >> 1) & 3);
      b[j] = *(const short8*)(Bsm + row * 32 + c4 * 8);
    }
#pragma unroll
    for (int i = 0; i < 4; ++i)
#pragma unroll
      for (int j = 0; j < 4; ++j)
        acc[i][j] = mfma16(a[i], b[j], acc[i][j]);
  }
}

// -------------------------------------------- 128^2 GEMM core, pipelined
// Kept for gemm_out only (r10/r11 config; untouched).
__device__ __forceinline__ void gemm128_pipe(const u16* __restrict__ A,
                                             const u16* __restrict__ Bt,
                                             int m0, int n0,
                                             u16* Asm, u16* Bsm,
                                             f32x4 acc[4][4]) {
  const int tid = threadIdx.x;
  const int w = tid >> 6;
  const int lane = tid & 63;
  const int quad = lane >> 4;
  const int l16 = lane & 15;
  const int wm = (w >> 1) * 64;
  const int wn = (w & 1) * 64;

#pragma unroll
  for (int i = 0; i < 4; ++i)
#pragma unroll
    for (int j = 0; j < 4; ++j) acc[i][j] = (f32x4){0.f, 0.f, 0.f, 0.f};

#define STG128(k0_, b_)                                                     \
  do {                                                                      \
    _Pragma("unroll")                                                       \
    for (int p = 0; p < 2; ++p) {                                           \
      int s = p * 256 + tid;                                                \
      int row = s >> 2;                                                     \
      int c4 = (s & 3) ^ ((row >> 1) & 3);                                  \
      cp16(A + (size_t)(m0 + row) * 1024 + (k0_) + c4 * 8,                  \
           Asm + (size_t)(b_) * 4096 + (p * 256 + w * 64) * 8);             \
      cp16(Bt + (size_t)(n0 + row) * 1024 + (k0_) + c4 * 8,                 \
           Bsm + (size_t)(b_) * 4096 + (p * 256 + w * 64) * 8);             \
    }                                                                       \
  } while (0)

  STG128(0, 0);
  STG128(32, 1);
  asm volatile("s_waitcnt vmcnt(4)" ::: "memory");  // tile 0 landed
  asm volatile("s_barrier" ::: "memory");

  for (int kt = 0; kt < 32; ++kt) {
    const u16* Ab = Asm + (kt & 1) * 4096;
    const u16* Bb = Bsm + (kt & 1) * 4096;
    short8 a[4], b[4];
#pragma unroll
    for (int i = 0; i < 4; ++i) {
      int row = wm + i * 16 + l16;
      int c4 = quad ^ ((row >> 1) & 3);
      a[i] = *(const short8*)(Ab + row * 32 + c4 * 8);
    }
#pragma unroll
    for (int j = 0; j < 4; ++j) {
      int row = wn + j * 16 + l16;
      int c4 = quad ^ ((row >> 1) & 3);
      b[j] = *(const short8*)(Bb + row * 32 + c4 * 8);
    }
#pragma unroll
    for (int i = 0; i < 4; ++i)
#pragma unroll
      for (int j = 0; j < 4; ++j)
        acc[i][j] = mfma16(a[i], b[j], acc[i][j]);

    asm volatile("s_barrier" ::: "memory");  // all waves done reading buf
    if (kt + 2 < 32) {
      STG128((kt + 2) * 32, kt & 1);         // into freed buf; stays in flight
      asm volatile("s_waitcnt vmcnt(4)" ::: "memory");  // tile kt+1 landed
    } else if (kt + 1 < 32) {
      asm volatile("s_waitcnt vmcnt(0)" ::: "memory");  // last tile: drain
    }
    asm volatile("s_barrier" ::: "memory");  // buf(kt+1) ready for all waves
  }
#undef STG128
}

// ---------------------------------------------------------------- QKV GEMM
// Flat mapping (r11). v-blocks (which==2, block-uniform) pack the 4
// consecutive-t stores into one aligned short4.
__global__ __launch_bounds__(256) void gemm_qkv_kernel(
    const u16* __restrict__ x, const u16* __restrict__ Wt,
    const float* __restrict__ bias,
    u16* __restrict__ qb, u16* __restrict__ kb, u16* __restrict__ vtb) {
  __shared__ __align__(16) u16 Asm[128 * 32];
  __shared__ __align__(16) u16 Bsm[128 * 32];
  f32x4 acc[4][4];
  const int m0 = blockIdx.y * 128;
  const int n0 = blockIdx.x * 128;
  gemm128_sync(x, Wt, m0, n0, Asm, Bsm, acc);

  const int tid = threadIdx.x;
  const int w = tid >> 6, lane = tid & 63, quad = lane >> 4, l16 = lane & 15;
  const int wm = (w >> 1) * 64, wn = (w & 1) * 64;
#pragma unroll
  for (int j = 0; j < 4; ++j) {
    int col = n0 + wn + j * 16 + l16;
    float bv = bias[col];
    int which = col >> 10;     // 0=q 1=k 2=v (block-uniform)
    int rem = col & 1023;
    int h = rem >> 6, d = rem & 63;
#pragma unroll
    for (int i = 0; i < 4; ++i) {
      int m4 = m0 + wm + i * 16 + quad * 4;    // aligned 4, within one seq
      int b_ = m4 >> 11, t4 = m4 & 2047;
      int bh = b_ * N_HEADS + h;
      if (which == 2) {
        short4v pk;
#pragma unroll
        for (int r = 0; r < 4; ++r) pk[r] = (short)f2b(acc[i][j][r] + bv);
        *(short4v*)(vtb + ((size_t)((bh << 6) + d)) * TSEQ + t4) = pk;
      } else {
        u16* dst = (which == 0) ? qb : kb;
#pragma unroll
        for (int r = 0; r < 4; ++r)
          dst[((size_t)(bh * TSEQ + t4 + r) << 6) + d] = f2b(acc[i][j][r] + bv);
      }
    }
  }
}

// ---------------------------------------------------------------- attention
// r15: 8 waves x 512 threads; wave w owns q rows qbase + w*16 .. +15 (one
// 16-row fragment). Same 128-row tile, swapped QK^T + bit-permuted K
// staging, P in-register; LDS 32KB double-buffer -> 4 blocks/CU x 8 waves
// = 32 waves/CU (full). STAGE: 1 K + 1 V cp16 per thread; mid-loop
// vmcnt(2). XCD-chunked swizzle + setprio kept.
__global__ __launch_bounds__(512, 8) void attn_kernel(const u16* __restrict__ qb,
                                                      const u16* __restrict__ kb,
                                                      const u16* __restrict__ vtb,
                                                      u16* __restrict__ ob) {
  const int flat = blockIdx.y * 16 + blockIdx.x;
  const int swz = (flat & 7) * 128 + (flat >> 3);   // bijective (1024%8==0)
  const int bh = swz >> 4;                          // 0..63
  const int qt = 15 - (swz & 15);                   // 15..0 heavy-first
  __shared__ __align__(16) u16 Ksm[2][4096];     // [buf][rho 64][d 64] swizzled
  __shared__ __align__(16) u16 Vsm[2][4096];     // [buf][d 64][t_k 64] swizzled
  const int tid = threadIdx.x;
  const int w = tid >> 6, lane = tid & 63, quad = lane >> 4, l16 = lane & 15;
  const int qbase = qt * 128;
  const int qmin = qbase + w * 16;                  // this wave's first q row

  // Q fragment (B-operand layout == A-layout for 16x16x32), in registers
  short8 qf0, qf1;
  {
    const u16* qr = qb + ((size_t)(bh * TSEQ + qmin + l16)) * 64;
    qf0 = *(const short8*)(qr + quad * 8);
    qf1 = *(const short8*)(qr + 32 + quad * 8);
  }

  f32x4 o[4];
  float lp = 0.f;
#pragma unroll
  for (int j = 0; j < 4; ++j) o[j] = (f32x4){0.f, 0.f, 0.f, 0.f};
  const float cexp = 0.18033688011112042f;  // (1/sqrt(64)) * log2(e)
  const float M = 10.0f;                    // static softmax shift

  const u16* kb_bh = kb + (size_t)bh * TSEQ * 64;
  const u16* vt_bh = vtb + (size_t)bh * 64 * TSEQ;
  const int nk = 2 * qt + 2;

  // stage k-tile kt into buffer b: 1 K + 1 V DMA per thread (vmcnt +=2).
  // 512 threads cover the 512 16B-chunks of each 8KB tile. K rows
  // bit-permuted: LDS row rho <- key kappa(rho); V rows natural (d).
#define STAGE(kt_, b_)                                                        \
  do {                                                                        \
    const u16* kbase_ = kb_bh + (size_t)((kt_) * 64) * 64;                    \
    const u16* vbase_ = vt_bh + (kt_) * 64;                                   \
    int row_ = tid >> 3;                                                      \
    int c8_ = (tid & 7) ^ (row_ & 7);                                         \
    int krow_ = (row_ & 0x23) | ((row_ & 0x0C) << 1) | ((row_ & 0x10) >> 2);  \
    cp16(kbase_ + krow_ * 64 + c8_ * 8, &Ksm[b_][w * 512]);                   \
    cp16(vbase_ + (size_t)row_ * TSEQ + c8_ * 8, &Vsm[b_][w * 512]);          \
  } while (0)

  STAGE(0, 0);

  for (int kt = 0; kt < nk; ++kt) {
    // barrier 1: all waves finished READING buf((kt+1)&1) in iter kt-1
    asm volatile("s_barrier" ::: "memory");
    if (kt + 1 < nk) {
      STAGE(kt + 1, (kt + 1) & 1);               // DMA for kt+1 (stays in flight)
      asm volatile("s_waitcnt vmcnt(2)" ::: "memory");  // tile kt landed
    } else {
      asm volatile("s_waitcnt vmcnt(0)" ::: "memory");  // last tile: drain
    }
    // barrier 2: all waves' tile-kt DMA landed
    asm volatile("s_barrier" ::: "memory");

    const u16* Kb = Ksm[kt & 1];
    const u16* Vb = Vsm[kt & 1];

    if (kt * 64 <= qmin + 15) {          // else whole fragment masked
      __builtin_amdgcn_s_setprio(1);
      const int qlane = qmin + l16;

      // S^T = K Q^T : lane (quad,l16) gets S[q=l16][kappa(j*16+quad*4+r)]
      f32x4 s[4];
#pragma unroll
      for (int j = 0; j < 4; ++j) {
        int row = j * 16 + l16;
        int ca = quad ^ (row & 7);
        int cb = (4 + quad) ^ (row & 7);
        short8 k0 = *(const short8*)(Kb + row * 64 + ca * 8);
        short8 k1 = *(const short8*)(Kb + row * 64 + cb * 8);
        f32x4 z = (f32x4){0.f, 0.f, 0.f, 0.f};
        z = mfma16(k0, qf0, z);
        z = mfma16(k1, qf1, z);
        s[j] = z;
      }
      if (kt * 64 + 63 > qmin) {  // diagonal overlap: elementwise causal mask
#pragma unroll
        for (int j = 0; j < 4; ++j) {
#pragma unroll
          for (int r = 0; r < 4; ++r) {
            int kabs = kt * 64 + ((j >> 1) << 5) + (quad << 3) + ((j & 1) << 2) + r;
            if (kabs > qlane) s[j][r] = -1e30f;
          }
        }
      }
      // static-max softmax: p = exp2(s*cexp - M); pack straight into the
      // PV A-operand fragments (keys already lane-local in k-slot order).
      short8 ap0, ap1;
#pragma unroll
      for (int j = 0; j < 4; ++j) {
#pragma unroll
        for (int r = 0; r < 4; ++r) {
          float p_ = __builtin_amdgcn_exp2f(__builtin_fmaf(s[j][r], cexp, -M));
          lp += p_;
          u16 pb = f2b(p_);
          if (j < 2) ap0[j * 4 + r] = (short)pb;
          else       ap1[(j - 2) * 4 + r] = (short)pb;
        }
      }
      // O += P V : A = P (rows q=l16, k = quad*8+e), B = V^T (cols d=l16)
#pragma unroll
      for (int j = 0; j < 4; ++j) {
        int row = j * 16 + l16;  // d
        int ca = quad ^ (row & 7);
        int cb = (4 + quad) ^ (row & 7);
        short8 v0 = *(const short8*)(Vb + row * 64 + ca * 8);
        short8 v1 = *(const short8*)(Vb + row * 64 + cb * 8);
        o[j] = mfma16(ap0, v0, o[j]);
        o[j] = mfma16(ap1, v1, o[j]);
      }
      __builtin_amdgcn_s_setprio(0);
    }
  }
#undef STAGE

  // epilogue: full softmax denominator = sum of lp across the 4 quads
  // (lane (quad,l16) holds the partial for q=l16 over keys quad*8+e, +32).
  lp += __shfl_xor(lp, 16);
  lp += __shfl_xor(lp, 32);
  const int b_ = bh >> 4, h = bh & 15;
  float dn[4];
#pragma unroll
  for (int r = 0; r < 4; ++r)
    dn[r] = __shfl(lp, (lane & 48) + quad * 4 + r);  // denom for q-row quad*4+r
#pragma unroll
  for (int j = 0; j < 4; ++j)
#pragma unroll
    for (int r = 0; r < 4; ++r) {
      int t = qmin + quad * 4 + r;
      int d = j * 16 + l16;
      ob[((size_t)(b_ * TSEQ + t)) * 1024 + h * 64 + d] =
          f2b(o[j][r] / dn[r]);
    }
}

// ------------------------------------------------------- out GEMM (fp32 out)
// Grid (8,64) = 512 blocks. XCD chunk = 8 m-panels x 8 n-tiles: A 2MB +
// B 2MB = 4MB L2 fit (kept from r13).
__global__ __launch_bounds__(256) void gemm_out_kernel(
    const u16* __restrict__ attn, const u16* __restrict__ Wt,
    const float* __restrict__ bias, float* __restrict__ out) {
  __shared__ __align__(16) u16 Asm[2 * 4096];
  __shared__ __align__(16) u16 Bsm[2 * 4096];
  f32x4 acc[4][4];
  const int flat = blockIdx.y * 8 + blockIdx.x;
  const int swz = (flat & 7) * 64 + (flat >> 3);    // bijective (512%8==0)
  const int m0 = (swz >> 3) * 128;
  const int n0 = (swz & 7) * 128;
  gemm128_pipe(attn, Wt, m0, n0, Asm, Bsm, acc);

  const int tid = threadIdx.x;
  const int w = tid >> 6, lane = tid & 63, quad = lane >> 4, l16 = lane & 15;
  const int wm = (w >> 1) * 64, wn = (w & 1) * 64;
#pragma unroll
  for (int j = 0; j < 4; ++j) {
    int col = n0 + wn + j * 16 + l16;
    float bv = bias[col];
#pragma unroll
    for (int i = 0; i < 4; ++i)
#pragma unroll
      for (int r = 0; r < 4; ++r) {
        int m = m0 + wm + i * 16 + quad * 4 + r;
        out[(size_t)m * 1024 + col] = acc[i][j][r] + bv;
      }
  }
}

// ---------------------------------------------------------------- launcher
extern "C" void kernel_launch(void* const* d_in, const int* in_sizes, int n_in,
                              void* d_out, int out_size, void* d_ws, size_t ws_size,
                              hipStream_t stream) {
  const float* x    = (const float*)d_in[0];   // [8192][1024] fp32
  const float* Wqkv = (const float*)d_in[1];   // [1024][3072] fp32
  const float* bqkv = (const float*)d_in[2];   // [3072] fp32
  const float* Wout = (const float*)d_in[3];   // [1024][1024] fp32
  const float* bout = (const float*)d_in[4];   // [1024] fp32
  float* out = (float*)d_out;                  // [8192][1024] fp32

  u16* ws = (u16*)d_ws;
  u16* xb     = ws;                                  // 8M   bf16 x
  u16* wqkv_t = xb + (size_t)MROWS * 1024;           // 3M   [3072][1024]
  u16* wout_t = wqkv_t + (size_t)N3 * 1024;          // 1M   [1024][1024]
  u16* qbuf   = wout_t + (size_t)1024 * 1024;        // 8M   [bh][t][d]
  u16* kbuf   = qbuf + (size_t)MROWS * 1024;         // 8M   [bh][t][d]
  u16* vtbuf  = kbuf + (size_t)MROWS * 1024;         // 8M   [bh][d][t]
  u16* obuf   = vtbuf + (size_t)MROWS * 1024;        // 8M   [b][t][c]
  (void)ws_size; (void)n_in; (void)in_sizes; (void)out_size;

  prep_kernel<<<PREP_TOTAL, 256, 0, stream>>>(x, xb, Wqkv, wqkv_t, Wout, wout_t);
  gemm_qkv_kernel<<<dim3(N3 / 128, MROWS / 128), 256, 0, stream>>>(xb, wqkv_t, bqkv, qbuf, kbuf, vtbuf);
  attn_kernel<<<dim3(TSEQ / 128, BATCH * N_HEADS), 512, 0, stream>>>(qbuf, kbuf, vtbuf, obuf);
  gemm_out_kernel<<<dim3(8, 64), 256, 0, stream>>>(obuf, wout_t, bout, out);
}